// Round 1
// baseline (415.319 us; speedup 1.0000x reference)
//
#include <hip/hip_runtime.h>

// ODE_23390391894829: batched RK4 integration of constant-curvature rod.
// Reference quirks replicated:
//  - actions[:,3:6] are NEVER used (loop re-reads segment 0 at n=0).
//  - lengths for BOTH segments come from l = L0 + actions[:,0].
//  - segment 2 continues the same trajectory from y_{L} (autonomous ODE,
//    constant u), so z_s == y_{L+s}.
// Output: (2T, B, 14) fp32, out[t,b] = traj[min(t,L)] (seg1) /
// traj[L + min(t,L)] (seg2). Channels 12,13 are constant (ux,uy).

#define C_L0 0.05f
#define C_D  0.0075f
#define C_DS 0.005f

__device__ __forceinline__ void ode_f(const float* __restrict__ y, float ux, float uy,
                                      float* __restrict__ d) {
    // dr = third column of R
    d[0] = y[5];
    d[1] = y[8];
    d[2] = y[11];
    // dR = R @ u_hat, u_hat = [[0,0,uy],[0,0,-ux],[-uy,ux,0]]
#pragma unroll
    for (int i = 0; i < 3; ++i) {
        float Ri0 = y[3 + 3 * i + 0];
        float Ri1 = y[3 + 3 * i + 1];
        float Ri2 = y[3 + 3 * i + 2];
        d[3 + 3 * i + 0] = -uy * Ri2;
        d[3 + 3 * i + 1] =  ux * Ri2;
        d[3 + 3 * i + 2] =  uy * Ri0 - ux * Ri1;
    }
}

__device__ __forceinline__ void rk4_step(float* __restrict__ y, float ux, float uy) {
    const float h = C_DS;
    float k1[12], k2[12], k3[12], k4[12], t[12];
    ode_f(y, ux, uy, k1);
#pragma unroll
    for (int i = 0; i < 12; ++i) t[i] = y[i] + (0.5f * h) * k1[i];
    ode_f(t, ux, uy, k2);
#pragma unroll
    for (int i = 0; i < 12; ++i) t[i] = y[i] + (0.5f * h) * k2[i];
    ode_f(t, ux, uy, k3);
#pragma unroll
    for (int i = 0; i < 12; ++i) t[i] = y[i] + h * k3[i];
    ode_f(t, ux, uy, k4);
    const float c = h / 6.0f;
#pragma unroll
    for (int i = 0; i < 12; ++i)
        y[i] = y[i] + c * (k1[i] + 2.0f * k2[i] + 2.0f * k3[i] + k4[i]);
}

__device__ __forceinline__ void write_row(float* __restrict__ out, int row, int b, int B,
                                          const float* __restrict__ y, float ux, float uy) {
    // 14 floats = 56 bytes per row-element; 56 % 8 == 0 -> float2 stores legal.
    float2* p = (float2*)(out + ((size_t)row * (size_t)B + (size_t)b) * 14);
    p[0] = make_float2(y[0], y[1]);
    p[1] = make_float2(y[2], y[3]);
    p[2] = make_float2(y[4], y[5]);
    p[3] = make_float2(y[6], y[7]);
    p[4] = make_float2(y[8], y[9]);
    p[5] = make_float2(y[10], y[11]);
    p[6] = make_float2(ux, uy);
}

__global__ void __launch_bounds__(256)
ode_kernel(const float* __restrict__ act, float* __restrict__ out, int B, int T) {
    int b = blockIdx.x * blockDim.x + threadIdx.x;
    if (b >= B) return;

    float a0 = act[b * 6 + 0];
    float a1 = act[b * 6 + 1];
    float a2 = act[b * 6 + 2];

    float l  = C_L0 + a0;
    float ld = l * C_D;
    float ux = a2 / (-ld);
    float uy = a1 / ld;
    int   L  = (int)floorf(l / C_DS);

    float y[12];
    y[0] = 0.f; y[1] = 0.f; y[2] = 0.f;
    y[3] = 1.f; y[4] = 0.f; y[5] = 0.f;
    y[6] = 0.f; y[7] = 1.f; y[8] = 0.f;
    y[9] = 0.f; y[10] = 0.f; y[11] = 1.f;

#pragma unroll
    for (int seg = 0; seg < 2; ++seg) {
        write_row(out, seg * T + 0, b, B, y, ux, uy);
        for (int t = 1; t < T; ++t) {
            if (t <= L) rk4_step(y, ux, uy);
            write_row(out, seg * T + t, b, B, y, ux, uy);
        }
    }
}

extern "C" void kernel_launch(void* const* d_in, const int* in_sizes, int n_in,
                              void* d_out, int out_size, void* d_ws, size_t ws_size,
                              hipStream_t stream) {
    const float* act = (const float*)d_in[0];
    float* out = (float*)d_out;
    int B = in_sizes[0] / 6;               // (B, 6) actions
    int T = out_size / (2 * 14 * B);       // output is (2T, B, 14)

    int threads = 256;
    int blocks = (B + threads - 1) / threads;
    hipLaunchKernelGGL(ode_kernel, dim3(blocks), dim3(threads), 0, stream,
                       act, out, B, T);
}

// Round 2
// 374.636 us; speedup vs baseline: 1.1086x; 1.1086x over previous
//
#include <hip/hip_runtime.h>

// ODE_23390391894829: batched RK4 integration of constant-curvature rod.
// Reference quirks replicated:
//  - actions[:,3:6] are NEVER used (reference loop re-reads segment 0 at n=0).
//  - lengths for BOTH segments come from l = L0 + actions[:,0].
//  - segment 2 continues the same trajectory (autonomous ODE, constant u).
// Output: (2T, B, 14) fp32, out[t] = traj[min(t,L)] per segment.
//
// R1->R2: LDS transpose staging. Per-thread rows are 56 B; direct stores are
// lane-strided by 56 B (-> ~56 cache lines per store instr, ~920 GB/s
// effective). Stage each row-chunk (256x14 f32) in LDS, store coalesced
// float4 (16 B/lane, lane-consecutive). Double buffer -> 1 barrier/row.

#define C_L0 0.05f
#define C_D  0.0075f
#define C_DS 0.005f
#define NB   256   // batch elements per block == block size

__device__ __forceinline__ void ode_f(const float* __restrict__ y, float ux, float uy,
                                      float* __restrict__ d) {
    d[0] = y[5];
    d[1] = y[8];
    d[2] = y[11];
#pragma unroll
    for (int i = 0; i < 3; ++i) {
        float Ri0 = y[3 + 3 * i + 0];
        float Ri1 = y[3 + 3 * i + 1];
        float Ri2 = y[3 + 3 * i + 2];
        d[3 + 3 * i + 0] = -uy * Ri2;
        d[3 + 3 * i + 1] =  ux * Ri2;
        d[3 + 3 * i + 2] =  uy * Ri0 - ux * Ri1;
    }
}

__device__ __forceinline__ void rk4_step(float* __restrict__ y, float ux, float uy) {
    const float h = C_DS;
    float k1[12], k2[12], k3[12], k4[12], t[12];
    ode_f(y, ux, uy, k1);
#pragma unroll
    for (int i = 0; i < 12; ++i) t[i] = y[i] + (0.5f * h) * k1[i];
    ode_f(t, ux, uy, k2);
#pragma unroll
    for (int i = 0; i < 12; ++i) t[i] = y[i] + (0.5f * h) * k2[i];
    ode_f(t, ux, uy, k3);
#pragma unroll
    for (int i = 0; i < 12; ++i) t[i] = y[i] + h * k3[i];
    ode_f(t, ux, uy, k4);
    const float c = h / 6.0f;
#pragma unroll
    for (int i = 0; i < 12; ++i)
        y[i] = y[i] + c * (k1[i] + 2.0f * k2[i] + 2.0f * k3[i] + k4[i]);
}

__global__ void __launch_bounds__(NB)
ode_kernel(const float* __restrict__ act, float* __restrict__ out, int B, int T) {
    __shared__ float lds[2][NB * 14];   // 2 x 14336 B

    const int tid = threadIdx.x;
    const int b   = blockIdx.x * NB + tid;   // B % NB == 0

    const float a0 = act[b * 6 + 0];
    const float a1 = act[b * 6 + 1];
    const float a2 = act[b * 6 + 2];

    const float l  = C_L0 + a0;
    const float ld = l * C_D;
    const float ux = a2 / (-ld);
    const float uy = a1 / ld;
    const int   L  = (int)floorf(l / C_DS);

    float y[12];
    y[0] = 0.f; y[1] = 0.f; y[2] = 0.f;
    y[3] = 1.f; y[4] = 0.f; y[5] = 0.f;
    y[6] = 0.f; y[7] = 1.f; y[8] = 0.f;
    y[9] = 0.f; y[10] = 0.f; y[11] = 1.f;

    int buf = 0;
#pragma unroll
    for (int seg = 0; seg < 2; ++seg) {
        for (int t = 0; t < T; ++t) {
            if (t >= 1 && t <= L) rk4_step(y, ux, uy);

            // Stage this thread's 14-float row into LDS (8B-aligned float2s).
            float2* dst = (float2*)&lds[buf][tid * 14];
            dst[0] = make_float2(y[0],  y[1]);
            dst[1] = make_float2(y[2],  y[3]);
            dst[2] = make_float2(y[4],  y[5]);
            dst[3] = make_float2(y[6],  y[7]);
            dst[4] = make_float2(y[8],  y[9]);
            dst[5] = make_float2(y[10], y[11]);
            dst[6] = make_float2(ux, uy);

            __syncthreads();

            // Coalesced store of the whole row-chunk: 896 float4s.
            const int row = seg * T + t;
            float4* __restrict__ g =
                (float4*)(out + ((size_t)row * (size_t)B + (size_t)blockIdx.x * NB) * 14);
            const float4* __restrict__ s = (const float4*)lds[buf];
            g[tid +   0] = s[tid +   0];
            g[tid + 256] = s[tid + 256];
            g[tid + 512] = s[tid + 512];
            if (tid < 128) g[tid + 768] = s[tid + 768];

            buf ^= 1;   // next row writes the other buffer; barrier above
                        // guarantees this row's reads finished before reuse
        }
    }
}

extern "C" void kernel_launch(void* const* d_in, const int* in_sizes, int n_in,
                              void* d_out, int out_size, void* d_ws, size_t ws_size,
                              hipStream_t stream) {
    const float* act = (const float*)d_in[0];
    float* out = (float*)d_out;
    int B = in_sizes[0] / 6;               // (B, 6) actions
    int T = out_size / (2 * 14 * B);       // output is (2T, B, 14)

    int blocks = B / NB;                   // B = 262144 -> 1024 blocks
    hipLaunchKernelGGL(ode_kernel, dim3(blocks), dim3(NB), 0, stream,
                       act, out, B, T);
}